// Round 5
// baseline (824.652 us; speedup 1.0000x reference)
//
#include <hip/hip_runtime.h>

#define NC 96
#define NC3 288
#define NH 256
#define NW 256
#define NHW 65536

typedef unsigned short ushort_t;
typedef __attribute__((ext_vector_type(8))) short bf16x8;
typedef __attribute__((ext_vector_type(4))) float f32x4;

__device__ __forceinline__ ushort_t f2bf(float x) {
  unsigned u = __float_as_uint(x);
  u += 0x7fffu + ((u >> 16) & 1u);
  return (ushort_t)(u >> 16);
}
__device__ __forceinline__ float bf2f(ushort_t h) {
  return __uint_as_float((unsigned)h << 16);
}

// ---------------- weight split-bf16 prep (once per launch) ----------------
__global__ __launch_bounds__(256) void k_wprep(
    const float* __restrict__ qkv_w, const float* __restrict__ proj_w,
    ushort_t* __restrict__ wq_hi, ushort_t* __restrict__ wq_lo,
    ushort_t* __restrict__ wp_hi, ushort_t* __restrict__ wp_lo) {
  const int id = blockIdx.x * 256 + threadIdx.x;
  if (id < NC3 * NC) {
    const float v = qkv_w[id];
    const ushort_t h = f2bf(v);
    wq_hi[id] = h;
    wq_lo[id] = f2bf(v - bf2f(h));
  } else {
    const int j = id - NC3 * NC;  // < NC*NC
    const float v = proj_w[j];
    const ushort_t h = f2bf(v);
    wp_hi[j] = h;
    wp_lo[j] = f2bf(v - bf2f(h));
  }
}

// ---------------- transpose [96][s] fp32 -> [s][96] split bf16 ----------------
__global__ __launch_bounds__(256) void k_xpose(
    const float* __restrict__ src, ushort_t* __restrict__ dst_hi,
    ushort_t* __restrict__ dst_lo) {
  __shared__ float ld[64 * 97];
  const int t = threadIdx.x;
  const int lane = t & 63, wave = t >> 6;
  const int sblk = blockIdx.x * 64;
  const int bz = blockIdx.y;
  const float* sb = src + (size_t)bz * NC * NHW + sblk;
#pragma unroll
  for (int i = 0; i < 24; ++i) {
    const int c = wave + i * 4;
    ld[lane * 97 + c] = sb[(size_t)c * NHW + lane];
  }
  __syncthreads();
  const size_t obase = ((size_t)bz * NHW + sblk) * NC;  // ushort index
  unsigned* oh = (unsigned*)(dst_hi + obase);
  unsigned* ol = (unsigned*)(dst_lo + obase);
#pragma unroll
  for (int p = 0; p < 12; ++p) {
    const int i = t + 256 * p;  // over 64*48 u32
    const int s = i / 48, cp = i - s * 48;
    const float f0 = ld[s * 97 + 2 * cp];
    const float f1 = ld[s * 97 + 2 * cp + 1];
    const ushort_t h0 = f2bf(f0), h1 = f2bf(f1);
    const ushort_t l0 = f2bf(f0 - bf2f(h0)), l1 = f2bf(f1 - bf2f(h1));
    oh[i] = (unsigned)h0 | ((unsigned)h1 << 16);
    ol[i] = (unsigned)l0 | ((unsigned)l1 << 16);
  }
}

// ---------------- 1x1 conv as split-bf16 MFMA GEMM, no LDS ----------------
// out[o][s] = sum_c w[o][c] * xT[s][c]; A=W, B=XT, D[m=o][n=s]
template <int OUTC>
__global__ __launch_bounds__(256, 4) void k_conv_mfma(
    const ushort_t* __restrict__ xt_hi, const ushort_t* __restrict__ xt_lo,
    const ushort_t* __restrict__ w_hi, const ushort_t* __restrict__ w_lo,
    const float* __restrict__ bias, float* __restrict__ out) {
  const int t = threadIdx.x;
  const int lane = t & 63;
  const int wave = t >> 6;
  const int bz = blockIdx.y;
  const int s0 = blockIdx.x * 128 + wave * 32;
  const size_t xbase = ((size_t)bz * NHW + s0) * NC;
  const int srow = (lane & 15) * NC + (lane >> 4) * 8;

  bf16x8 bH[2][3], bL[2][3];
#pragma unroll
  for (int nt = 0; nt < 2; ++nt)
#pragma unroll
    for (int k = 0; k < 3; ++k) {
      const size_t off = xbase + (size_t)nt * 16 * NC + srow + k * 32;
      bH[nt][k] = *(const bf16x8*)(xt_hi + off);
      bL[nt][k] = *(const bf16x8*)(xt_lo + off);
    }

  float* ob = out + (size_t)bz * OUTC * NHW + s0 + (lane & 15);
#pragma unroll 1
  for (int c3 = 0; c3 < OUTC / 96; ++c3) {
    const int o0 = c3 * 96;
    f32x4 acc[6][2];
#pragma unroll
    for (int m = 0; m < 6; ++m)
#pragma unroll
      for (int nt = 0; nt < 2; ++nt) acc[m][nt] = (f32x4){0.f, 0.f, 0.f, 0.f};
#pragma unroll
    for (int k = 0; k < 3; ++k) {
#pragma unroll
      for (int m = 0; m < 6; ++m) {
        const int wrow = (o0 + m * 16 + (lane & 15)) * NC + k * 32 + (lane >> 4) * 8;
        const bf16x8 aH = *(const bf16x8*)(w_hi + wrow);
        const bf16x8 aL = *(const bf16x8*)(w_lo + wrow);
#pragma unroll
        for (int nt = 0; nt < 2; ++nt) {
          acc[m][nt] = __builtin_amdgcn_mfma_f32_16x16x32_bf16(aH, bH[nt][k], acc[m][nt], 0, 0, 0);
          acc[m][nt] = __builtin_amdgcn_mfma_f32_16x16x32_bf16(aH, bL[nt][k], acc[m][nt], 0, 0, 0);
          acc[m][nt] = __builtin_amdgcn_mfma_f32_16x16x32_bf16(aL, bH[nt][k], acc[m][nt], 0, 0, 0);
        }
      }
    }
#pragma unroll
    for (int m = 0; m < 6; ++m) {
      const int orow = o0 + m * 16 + (lane >> 4) * 4;
#pragma unroll
      for (int r = 0; r < 4; ++r) {
        const float bs = bias[orow + r];
#pragma unroll
        for (int nt = 0; nt < 2; ++nt)
          ob[(size_t)(orow + r) * NHW + nt * 16] = acc[m][nt][r] + bs;
      }
    }
  }
}

// ---------------- depthwise 3x3, pad=1; V channels -> split bf16 tiled ----
__global__ __launch_bounds__(256) void k_dw2(
    const float* __restrict__ in, const float* __restrict__ w,
    const float* __restrict__ bias, float* __restrict__ out_qk,
    ushort_t* __restrict__ v_hi, ushort_t* __restrict__ v_lo) {
  __shared__ float s[10][NW + 2];
  const int t = threadIdx.x;
  const int bc = blockIdx.y;
  const int b = bc / NC3, ch = bc % NC3;
  const int h0 = blockIdx.x * 8;
  const float* ib = in + (size_t)bc * NHW;
  for (int idx = t; idx < 10 * (NW + 2); idx += 256) {
    const int r = idx / (NW + 2), cc = idx % (NW + 2);
    const int gh = h0 + r - 1, gw = cc - 1;
    float v = 0.f;
    if (gh >= 0 && gh < NH && gw >= 0 && gw < NW) v = ib[gh * NW + gw];
    s[r][cc] = v;
  }
  __syncthreads();
  float wr[9];
#pragma unroll
  for (int k = 0; k < 9; ++k) wr[k] = w[ch * 9 + k];
  const float bs = bias[ch];
  if (ch < 192) {
    float* ob = out_qk + ((size_t)(b * 192 + ch)) * NHW + (size_t)h0 * NW + t;
#pragma unroll
    for (int r = 0; r < 8; ++r) {
      float a = bs;
#pragma unroll
      for (int dr = 0; dr < 3; ++dr)
#pragma unroll
        for (int dc = 0; dc < 3; ++dc)
          a = fmaf(s[r + dr][t + dc], wr[dr * 3 + dc], a);
      ob[r * NW] = a;
    }
  } else {
    const int bcv = b * NC + (ch - 192);
    const size_t base = (size_t)bcv * NHW + (size_t)(t >> 5) * 8192 + (t & 31);
#pragma unroll
    for (int r = 0; r < 8; ++r) {
      float a = bs;
#pragma unroll
      for (int dr = 0; dr < 3; ++dr)
#pragma unroll
        for (int dc = 0; dc < 3; ++dc)
          a = fmaf(s[r + dr][t + dc], wr[dr * 3 + dc], a);
      const ushort_t hi = f2bf(a);
      const ushort_t lo = f2bf(a - bf2f(hi));
      v_hi[base + (size_t)(h0 + r) * 32] = hi;
      v_lo[base + (size_t)(h0 + r) * 32] = lo;
    }
  }
}

// ---------------- prep: L2-norm over h + scale + bf16 split + transpose ----
__global__ __launch_bounds__(256) void k_prep(
    const float* __restrict__ src_qk, const float* __restrict__ temp,
    ushort_t* __restrict__ qt_hi, ushort_t* __restrict__ qt_lo,
    ushort_t* __restrict__ kt_hi, ushort_t* __restrict__ kt_lo) {
  __shared__ float trans[32][257];
  __shared__ float sums[8][32];
  __shared__ float inv[32];
  const int t = threadIdx.x;
  const int sw = blockIdx.x;
  const int qk = blockIdx.y;
  const int bc = blockIdx.z;
  const int b = bc / NC, c = bc % NC;
  const float* src = src_qk + ((size_t)(b * 192 + qk * 96 + c)) * NHW + sw * 32;
  const int wl = t & 31, hg = t >> 5;
  float ss = 0.f;
  for (int i = 0; i < 32; ++i) {
    const int h = i * 8 + hg;
    const float v = src[(size_t)h * NW + wl];
    trans[wl][h] = v;
    ss = fmaf(v, v, ss);
  }
  sums[hg][wl] = ss;
  __syncthreads();
  if (t < 32) {
    float tot = 0.f;
#pragma unroll
    for (int g = 0; g < 8; ++g) tot += sums[g][t];
    float iv = 1.f / fmaxf(sqrtf(tot), 1e-12f);
    if (qk) iv *= temp[c];
    inv[t] = iv;
  }
  __syncthreads();
  const float iv = inv[wl];
  const int hb = hg;
  ushort_t* dh = (qk ? kt_hi : qt_hi) + (size_t)bc * NHW + (size_t)hb * 8192 +
                 (size_t)(sw * 32 + wl) * 32;
  ushort_t* dl = (qk ? kt_lo : qt_lo) + (size_t)bc * NHW + (size_t)hb * 8192 +
                 (size_t)(sw * 32 + wl) * 32;
#pragma unroll
  for (int j4 = 0; j4 < 4; ++j4) {
    uint4 ph, pl;
    unsigned* pph = (unsigned*)&ph;
    unsigned* ppl = (unsigned*)&pl;
#pragma unroll
    for (int e2 = 0; e2 < 4; ++e2) {
      const float f0 = trans[wl][hb * 32 + j4 * 8 + 2 * e2] * iv;
      const float f1 = trans[wl][hb * 32 + j4 * 8 + 2 * e2 + 1] * iv;
      const ushort_t h0 = f2bf(f0), h1 = f2bf(f1);
      const ushort_t l0 = f2bf(f0 - bf2f(h0)), l1 = f2bf(f1 - bf2f(h1));
      pph[e2] = (unsigned)h0 | ((unsigned)h1 << 16);
      ppl[e2] = (unsigned)l0 | ((unsigned)l1 << 16);
    }
    *(uint4*)(dh + j4 * 8) = ph;
    *(uint4*)(dl + j4 * 8) = pl;
  }
}

// ---------------- attn: S = QT*K (split-bf16 MFMA), col-softmax over w ----
__global__ __launch_bounds__(256, 3) void k_attn_mfma(
    const ushort_t* __restrict__ qt_hi, const ushort_t* __restrict__ qt_lo,
    const ushort_t* __restrict__ kt_hi, const ushort_t* __restrict__ kt_lo,
    ushort_t* __restrict__ pt_hi, ushort_t* __restrict__ pt_lo) {
  __shared__ __align__(16) char smem[52352];
  ushort_t* qh = (ushort_t*)smem;
  ushort_t* ql = (ushort_t*)(smem + 20480);
  ushort_t* kh = (ushort_t*)(smem + 40960);
  ushort_t* kl = (ushort_t*)(smem + 46080);
  float* red = (float*)(smem + 51200);
  ushort_t* pts = (ushort_t*)smem;

  const int t = threadIdx.x;
  const int lane = t & 63;
  const int wid = t >> 6;
  const int bc = blockIdx.x;
  const int v0 = blockIdx.y * 64;
  const size_t base_q = (size_t)bc * NHW;
  const size_t base_k = (size_t)bc * NHW + (size_t)v0 * 32;

  f32x4 acc[4][4];
#pragma unroll
  for (int mt = 0; mt < 4; ++mt)
#pragma unroll
    for (int nt = 0; nt < 4; ++nt) acc[mt][nt] = (f32x4){0.f, 0.f, 0.f, 0.f};

  for (int hb = 0; hb < 8; ++hb) {
    {
      const ushort_t* gq = qt_hi + base_q + hb * 8192 + t * 32;
      const ushort_t* gl = qt_lo + base_q + hb * 8192 + t * 32;
      uint4* dh = (uint4*)(qh + t * 40);
      uint4* dl = (uint4*)(ql + t * 40);
#pragma unroll
      for (int j = 0; j < 4; ++j) {
        dh[j] = *(const uint4*)(gq + j * 8);
        dl[j] = *(const uint4*)(gl + j * 8);
      }
      if (t < 64) {
        const ushort_t* gk = kt_hi + base_k + hb * 8192 + t * 32;
        uint4* dk = (uint4*)(kh + t * 40);
#pragma unroll
        for (int j = 0; j < 4; ++j) dk[j] = *(const uint4*)(gk + j * 8);
      } else if (t < 128) {
        const int r = t - 64;
        const ushort_t* gk = kt_lo + base_k + hb * 8192 + r * 32;
        uint4* dk = (uint4*)(kl + r * 40);
#pragma unroll
        for (int j = 0; j < 4; ++j) dk[j] = *(const uint4*)(gk + j * 8);
      }
    }
    __syncthreads();
    bf16x8 aH[4], aL[4];
#pragma unroll
    for (int mt = 0; mt < 4; ++mt) {
      const int off = (wid * 64 + mt * 16 + (lane & 15)) * 40 + (lane >> 4) * 8;
      aH[mt] = *(const bf16x8*)(qh + off);
      aL[mt] = *(const bf16x8*)(ql + off);
    }
#pragma unroll
    for (int nt = 0; nt < 4; ++nt) {
      const int off = (nt * 16 + (lane & 15)) * 40 + (lane >> 4) * 8;
      const bf16x8 bH = *(const bf16x8*)(kh + off);
      const bf16x8 bL = *(const bf16x8*)(kl + off);
#pragma unroll
      for (int mt = 0; mt < 4; ++mt) {
        acc[mt][nt] = __builtin_amdgcn_mfma_f32_16x16x32_bf16(aH[mt], bH, acc[mt][nt], 0, 0, 0);
        acc[mt][nt] = __builtin_amdgcn_mfma_f32_16x16x32_bf16(aH[mt], bL, acc[mt][nt], 0, 0, 0);
        acc[mt][nt] = __builtin_amdgcn_mfma_f32_16x16x32_bf16(aL[mt], bH, acc[mt][nt], 0, 0, 0);
      }
    }
    __syncthreads();
  }

  float Mv[4], Sv[4];
#pragma unroll
  for (int nt = 0; nt < 4; ++nt) {
    float m = -3.4e38f;
#pragma unroll
    for (int mt = 0; mt < 4; ++mt)
#pragma unroll
      for (int r = 0; r < 4; ++r) m = fmaxf(m, acc[mt][nt][r]);
    m = fmaxf(m, __shfl_xor(m, 16));
    m = fmaxf(m, __shfl_xor(m, 32));
    if (lane < 16) red[wid * 64 + nt * 16 + lane] = m;
  }
  __syncthreads();
#pragma unroll
  for (int nt = 0; nt < 4; ++nt) {
    const int vl = nt * 16 + (lane & 15);
    Mv[nt] = fmaxf(fmaxf(red[vl], red[64 + vl]),
                   fmaxf(red[128 + vl], red[192 + vl]));
  }
  __syncthreads();
#pragma unroll
  for (int nt = 0; nt < 4; ++nt) {
    float s = 0.f;
#pragma unroll
    for (int mt = 0; mt < 4; ++mt)
#pragma unroll
      for (int r = 0; r < 4; ++r) {
        const float p = __expf(acc[mt][nt][r] - Mv[nt]);
        acc[mt][nt][r] = p;
        s += p;
      }
    s += __shfl_xor(s, 16);
    s += __shfl_xor(s, 32);
    if (lane < 16) red[wid * 64 + nt * 16 + lane] = s;
  }
  __syncthreads();
#pragma unroll
  for (int nt = 0; nt < 4; ++nt) {
    const int vl = nt * 16 + (lane & 15);
    Sv[nt] = 1.f / (red[vl] + red[64 + vl] + red[128 + vl] + red[192 + vl]);
  }
#pragma unroll
  for (int nt = 0; nt < 4; ++nt)
#pragma unroll
    for (int mt = 0; mt < 4; ++mt)
#pragma unroll
      for (int r = 0; r < 4; ++r) acc[mt][nt][r] *= Sv[nt];
  __syncthreads();

  for (int pass = 0; pass < 2; ++pass) {
#pragma unroll
    for (int nt = 0; nt < 4; ++nt)
#pragma unroll
      for (int mt = 0; mt < 4; ++mt) {
        ushort_t pk[4];
#pragma unroll
        for (int r = 0; r < 4; ++r) {
          const float p = acc[mt][nt][r];
          const ushort_t hi = f2bf(p);
          pk[r] = pass == 0 ? hi : f2bf(p - bf2f(hi));
        }
        const int v = nt * 16 + (lane & 15);
        const int wb2 = wid * 64 + mt * 16 + ((lane >> 4) << 2);
        *(ushort4*)(pts + v * 264 + wb2) =
            make_ushort4(pk[0], pk[1], pk[2], pk[3]);
      }
    __syncthreads();
    ushort_t* dst = pass == 0 ? pt_hi : pt_lo;
#pragma unroll
    for (int i = 0; i < 2; ++i) {
      const int cid = t + (i << 8);
      const int wb = cid >> 6, v = cid & 63;
      const ushort_t* sp = pts + v * 264 + wb * 32;
      ushort_t* d = dst + (size_t)bc * NHW + (size_t)wb * 8192 +
                    (size_t)(v0 + v) * 32;
#pragma unroll
      for (int j = 0; j < 4; ++j) *(uint4*)(d + j * 8) = *(const uint4*)(sp + j * 8);
    }
    __syncthreads();
  }
}

// ---------------- out[h][v] = sum_w V[h][w] * P[w][v], split-bf16 MFMA ----
__global__ __launch_bounds__(256, 3) void k_av_mfma(
    const ushort_t* __restrict__ v_hi, const ushort_t* __restrict__ v_lo,
    const ushort_t* __restrict__ pt_hi, const ushort_t* __restrict__ pt_lo,
    float* __restrict__ aout) {
  __shared__ __align__(16) ushort_t vh[128 * 40];
  __shared__ __align__(16) ushort_t vl[128 * 40];
  __shared__ __align__(16) ushort_t ph[128 * 40];
  __shared__ __align__(16) ushort_t pl[128 * 40];
  const int t = threadIdx.x;
  const int lane = t & 63;
  const int wid = t >> 6;
  const int bc = blockIdx.x;
  const int h0 = (blockIdx.y >> 1) * 128, v0 = (blockIdx.y & 1) * 128;
  const int wh = wid >> 1, wv = wid & 1;

  f32x4 acc[4][4];
#pragma unroll
  for (int mt = 0; mt < 4; ++mt)
#pragma unroll
    for (int nt = 0; nt < 4; ++nt) acc[mt][nt] = (f32x4){0.f, 0.f, 0.f, 0.f};

  for (int wb = 0; wb < 8; ++wb) {
#pragma unroll
    for (int i = 0; i < 2; ++i) {
      const int id = t + (i << 8);
      const int arr = id >> 7, row = id & 127;
      const ushort_t* g;
      ushort_t* d;
      if (arr == 0) {
        g = v_hi + (size_t)bc * NHW + (size_t)wb * 8192 + (size_t)(h0 + row) * 32;
        d = vh + row * 40;
      } else if (arr == 1) {
        g = v_lo + (size_t)bc * NHW + (size_t)wb * 8192 + (size_t)(h0 + row) * 32;
        d = vl + row * 40;
      } else if (arr == 2) {
        g = pt_hi + (size_t)bc * NHW + (size_t)wb * 8192 + (size_t)(v0 + row) * 32;
        d = ph + row * 40;
      } else {
        g = pt_lo + (size_t)bc * NHW + (size_t)wb * 8192 + (size_t)(v0 + row) * 32;
        d = pl + row * 40;
      }
#pragma unroll
      for (int j = 0; j < 4; ++j)
        *(uint4*)(d + j * 8) = *(const uint4*)(g + j * 8);
    }
    __syncthreads();
    bf16x8 aH[4], aL[4];
#pragma unroll
    for (int mt = 0; mt < 4; ++mt) {
      const int off = (wh * 64 + mt * 16 + (lane & 15)) * 40 + (lane >> 4) * 8;
      aH[mt] = *(const bf16x8*)(vh + off);
      aL[mt] = *(const bf16x8*)(vl + off);
    }
#pragma unroll
    for (int nt = 0; nt < 4; ++nt) {
      const int off = (wv * 64 + nt * 16 + (lane & 15)) * 40 + (lane >> 4) * 8;
      const bf16x8 bH = *(const bf16x8*)(ph + off);
      const bf16x8 bL = *(const bf16x8*)(pl + off);
#pragma unroll
      for (int mt = 0; mt < 4; ++mt) {
        acc[mt][nt] = __builtin_amdgcn_mfma_f32_16x16x32_bf16(aH[mt], bH, acc[mt][nt], 0, 0, 0);
        acc[mt][nt] = __builtin_amdgcn_mfma_f32_16x16x32_bf16(aH[mt], bL, acc[mt][nt], 0, 0, 0);
        acc[mt][nt] = __builtin_amdgcn_mfma_f32_16x16x32_bf16(aL[mt], bH, acc[mt][nt], 0, 0, 0);
      }
    }
    __syncthreads();
  }

#pragma unroll
  for (int mt = 0; mt < 4; ++mt) {
    const int hbase = h0 + wh * 64 + mt * 16 + ((lane >> 4) << 2);
#pragma unroll
    for (int nt = 0; nt < 4; ++nt) {
      const int vv = v0 + wv * 64 + nt * 16 + (lane & 15);
      float* o = aout + (size_t)bc * NHW + (size_t)hbase * NW + vv;
#pragma unroll
      for (int r = 0; r < 4; ++r) o[(size_t)r * NW] = acc[mt][nt][r];
    }
  }
}

extern "C" void kernel_launch(void* const* d_in, const int* in_sizes, int n_in,
                              void* d_out, int out_size, void* d_ws,
                              size_t ws_size, hipStream_t stream) {
  const float* x = (const float*)d_in[0];
  const float* qkv_w = (const float*)d_in[1];
  const float* qkv_b = (const float*)d_in[2];
  const float* dw_w = (const float*)d_in[3];
  const float* dw_b = (const float*)d_in[4];
  const float* temp = (const float*)d_in[5];
  const float* proj_w = (const float*)d_in[6];
  const float* proj_b = (const float*)d_in[7];
  float* out = (float*)d_out;

  auto need = [](int nb) -> size_t {
    return (size_t)nb * NHW * 4ull * (NC3 + 192) +
           (size_t)nb * NC * NHW * 4ull +
           2ull * (NC3 * NC + NC * NC) * 2ull;
  };
  int nb = 1;
  if (need(4) <= ws_size) nb = 4;
  else if (need(2) <= ws_size) nb = 2;

  float* ws = (float*)d_ws;
  const size_t RAW = (size_t)nb * NC3 * NHW;   // floats
  const size_t QKF = (size_t)nb * 192 * NHW;   // floats
  float* qkv_raw = ws;
  float* dw_qk = ws + RAW;
  ushort_t* v_hi = (ushort_t*)(ws + RAW + QKF);
  ushort_t* v_lo = v_hi + (size_t)nb * NC * NHW;
  ushort_t* wq_hi = v_lo + (size_t)nb * NC * NHW;
  ushort_t* wq_lo = wq_hi + NC3 * NC;
  ushort_t* wp_hi = wq_lo + NC3 * NC;
  ushort_t* wp_lo = wp_hi + NC * NC;
  // aliases into dead regions:
  ushort_t* qt_hi = (ushort_t*)ws;                     // raw (dead after dw)
  ushort_t* qt_lo = qt_hi + (size_t)nb * NC * NHW;
  ushort_t* kt_hi = qt_lo + (size_t)nb * NC * NHW;
  ushort_t* kt_lo = kt_hi + (size_t)nb * NC * NHW;
  ushort_t* pt_hi = (ushort_t*)dw_qk;                  // dw_qk 1st half
  ushort_t* pt_lo = pt_hi + (size_t)nb * NC * NHW;
  ushort_t* xT_hi = (ushort_t*)(dw_qk + (size_t)nb * NC * NHW);  // dw_qk 2nd half
  ushort_t* xT_lo = xT_hi + (size_t)nb * NHW * NC;
  float* aout = ws + (size_t)nb * NC * NHW * 2;        // raw tail
  ushort_t* aT_hi = v_hi;                              // V dead after av
  ushort_t* aT_lo = v_lo;

  k_wprep<<<dim3(144), 256, 0, stream>>>(qkv_w, proj_w, wq_hi, wq_lo, wp_hi, wp_lo);

  const int BC = nb * NC;
  for (int b0 = 0; b0 < 4; b0 += nb) {
    const float* xb = x + (size_t)b0 * NC * NHW;
    float* outb = out + (size_t)b0 * NC * NHW;
    k_xpose<<<dim3(NHW / 64, nb), 256, 0, stream>>>(xb, xT_hi, xT_lo);
    k_conv_mfma<NC3><<<dim3(NHW / 128, nb), 256, 0, stream>>>(
        xT_hi, xT_lo, wq_hi, wq_lo, qkv_b, qkv_raw);
    k_dw2<<<dim3(32, nb * NC3), 256, 0, stream>>>(qkv_raw, dw_w, dw_b, dw_qk, v_hi, v_lo);
    k_prep<<<dim3(8, 2, BC), 256, 0, stream>>>(dw_qk, temp, qt_hi, qt_lo, kt_hi, kt_lo);
    k_attn_mfma<<<dim3(BC, 4), 256, 0, stream>>>(qt_hi, qt_lo, kt_hi, kt_lo, pt_hi, pt_lo);
    k_av_mfma<<<dim3(BC, 4), 256, 0, stream>>>(v_hi, v_lo, pt_hi, pt_lo, aout);
    k_xpose<<<dim3(NHW / 64, nb), 256, 0, stream>>>(aout, aT_hi, aT_lo);
    k_conv_mfma<NC><<<dim3(NHW / 128, nb), 256, 0, stream>>>(
        aT_hi, aT_lo, wp_hi, wp_lo, proj_b, outb);
  }
}

// Round 6
// 669.030 us; speedup vs baseline: 1.2326x; 1.2326x over previous
//
#include <hip/hip_runtime.h>

#define NC 96
#define NC3 288
#define NH 256
#define NW 256
#define NHW 65536

typedef unsigned short ushort_t;
typedef __attribute__((ext_vector_type(8))) short bf16x8;
typedef __attribute__((ext_vector_type(4))) float f32x4;

__device__ __forceinline__ ushort_t f2bf(float x) {
  unsigned u = __float_as_uint(x);
  u += 0x7fffu + ((u >> 16) & 1u);
  return (ushort_t)(u >> 16);
}
__device__ __forceinline__ float bf2f(ushort_t h) {
  return __uint_as_float((unsigned)h << 16);
}

// ---------------- weight split-bf16 prep (once per launch) ----------------
__global__ __launch_bounds__(256) void k_wprep(
    const float* __restrict__ qkv_w, const float* __restrict__ proj_w,
    ushort_t* __restrict__ wq_hi, ushort_t* __restrict__ wq_lo,
    ushort_t* __restrict__ wp_hi, ushort_t* __restrict__ wp_lo) {
  const int id = blockIdx.x * 256 + threadIdx.x;
  if (id < NC3 * NC) {
    const float v = qkv_w[id];
    const ushort_t h = f2bf(v);
    wq_hi[id] = h;
    wq_lo[id] = f2bf(v - bf2f(h));
  } else {
    const int j = id - NC3 * NC;  // < NC*NC
    const float v = proj_w[j];
    const ushort_t h = f2bf(v);
    wp_hi[j] = h;
    wp_lo[j] = f2bf(v - bf2f(h));
  }
}

// ---------------- 1x1 conv: fused transpose + split-bf16 MFMA GEMM ----------
// Reads in [b][c][s] fp32 native. Per block: 64-s tile, all OUTC channels.
// TILED: out[(b*1024+sblk)][OUTC][64] contiguous; else out[b][o][s].
template <int OUTC, bool TILED>
__global__ __launch_bounds__(256, 3) void k_conv(
    const float* __restrict__ in, const ushort_t* __restrict__ w_hi,
    const ushort_t* __restrict__ w_lo, const float* __restrict__ bias,
    float* __restrict__ out) {
  __shared__ float xt[96][66];
  __shared__ __align__(16) ushort_t xh[64][104];
  __shared__ __align__(16) ushort_t xl[64][104];
  const int t = threadIdx.x;
  const int bz = blockIdx.y;
  const int sblk = blockIdx.x;
  const int s0 = sblk * 64;
  const float* xb = in + (size_t)bz * NC * NHW + s0;
#pragma unroll
  for (int i = 0; i < 6; ++i) {
    const int idx = t + 256 * i;  // 1536 float4 = 96 rows x 16
    const int row = idx >> 4, c4 = (idx & 15) << 2;
    *(float4*)&xt[row][c4] = *(const float4*)&xb[(size_t)row * NHW + c4];
  }
  __syncthreads();
  {
    const int s = t & 63, cg = t >> 6;
#pragma unroll
    for (int i = 0; i < 12; ++i) {
      const int c = cg * 24 + i * 2;
      const float f0 = xt[c][s], f1 = xt[c + 1][s];
      const ushort_t h0 = f2bf(f0), h1 = f2bf(f1);
      const ushort_t l0 = f2bf(f0 - bf2f(h0)), l1 = f2bf(f1 - bf2f(h1));
      *(unsigned*)&xh[s][c] = (unsigned)h0 | ((unsigned)h1 << 16);
      *(unsigned*)&xl[s][c] = (unsigned)l0 | ((unsigned)l1 << 16);
    }
  }
  __syncthreads();
  const int lane = t & 63, wave = t >> 6;
  bf16x8 bH[3], bL[3];
  {
    const int srow = wave * 16 + (lane & 15);
    const int kof = (lane >> 4) * 8;
#pragma unroll
    for (int kk = 0; kk < 3; ++kk) {
      bH[kk] = *(const bf16x8*)&xh[srow][kk * 32 + kof];
      bL[kk] = *(const bf16x8*)&xl[srow][kk * 32 + kof];
    }
  }
  constexpr int M = OUTC / 16;
  f32x4 acc[M];
#pragma unroll
  for (int m = 0; m < M; ++m) acc[m] = (f32x4){0.f, 0.f, 0.f, 0.f};
  const int akof = (lane >> 4) * 8;
#pragma unroll
  for (int kk = 0; kk < 3; ++kk) {
#pragma unroll
    for (int m = 0; m < M; ++m) {
      const int wi = (m * 16 + (lane & 15)) * NC + kk * 32 + akof;
      const bf16x8 aH = *(const bf16x8*)(w_hi + wi);
      const bf16x8 aL = *(const bf16x8*)(w_lo + wi);
      acc[m] = __builtin_amdgcn_mfma_f32_16x16x32_bf16(aH, bH[kk], acc[m], 0, 0, 0);
      acc[m] = __builtin_amdgcn_mfma_f32_16x16x32_bf16(aH, bL[kk], acc[m], 0, 0, 0);
      acc[m] = __builtin_amdgcn_mfma_f32_16x16x32_bf16(aL, bH[kk], acc[m], 0, 0, 0);
    }
  }
  const int sl = wave * 16 + (lane & 15);
  if (TILED) {
    float* ob = out + ((size_t)(bz * 1024 + sblk)) * OUTC * 64 + sl;
#pragma unroll
    for (int m = 0; m < M; ++m) {
      const int o2 = m * 16 + (lane >> 4) * 4;
#pragma unroll
      for (int r = 0; r < 4; ++r)
        ob[(size_t)(o2 + r) * 64] = acc[m][r] + bias[o2 + r];
    }
  } else {
    float* ob = out + (size_t)bz * OUTC * NHW + s0 + sl;
#pragma unroll
    for (int m = 0; m < M; ++m) {
      const int o2 = m * 16 + (lane >> 4) * 4;
#pragma unroll
      for (int r = 0; r < 4; ++r)
        ob[(size_t)(o2 + r) * NHW] = acc[m][r] + bias[o2 + r];
    }
  }
}

// ---------------- depthwise 3x3 + layout emit + norm partials ----------------
// Block: one ch, 32 h x 256 w. Reads tiled qkv [b*1024+chunk][288][64].
// q/k -> qt/kt [bc][hb][w][32h] split bf16 + nq/nk partials [bc][hb][w]
// v   -> v     [bc][wb][h][32w] split bf16
__global__ __launch_bounds__(256, 4) void k_dw3(
    const float* __restrict__ qkvt, const float* __restrict__ w,
    const float* __restrict__ bias, ushort_t* __restrict__ qt_hi,
    ushort_t* __restrict__ qt_lo, ushort_t* __restrict__ kt_hi,
    ushort_t* __restrict__ kt_lo, ushort_t* __restrict__ v_hi,
    ushort_t* __restrict__ v_lo, float* __restrict__ nq_p,
    float* __restrict__ nk_p) {
  __shared__ float sd[34][258];
  const int t = threadIdx.x;
  const int hb = blockIdx.x;
  const int bcc = blockIdx.y;
  const int b = bcc / NC3, ch = bcc % NC3;
  const int h0 = hb * 32;
  const float* src = qkvt + (size_t)b * 1024 * NC3 * 64 + (size_t)ch * 64;
  for (int idx = t; idx < 34 * 258; idx += 256) {
    const int r = idx / 258, wo = idx - r * 258;
    const int gh = h0 + r - 1, gw = wo - 1;
    float v = 0.f;
    if (gh >= 0 && gh < 256 && gw >= 0 && gw < 256) {
      const int s = gh * 256 + gw;
      v = src[(size_t)(s >> 6) * (NC3 * 64) + (s & 63)];
    }
    sd[r][wo] = v;
  }
  __syncthreads();
  float wr[9];
#pragma unroll
  for (int k = 0; k < 9; ++k) wr[k] = w[ch * 9 + k];
  const float bs = bias[ch];
  const int wl = t;
  float res[32];
  float r0a = sd[0][wl], r0b = sd[0][wl + 1], r0c = sd[0][wl + 2];
  float r1a = sd[1][wl], r1b = sd[1][wl + 1], r1c = sd[1][wl + 2];
#pragma unroll
  for (int r = 0; r < 32; ++r) {
    const float r2a = sd[r + 2][wl], r2b = sd[r + 2][wl + 1],
                r2c = sd[r + 2][wl + 2];
    float a = bs;
    a = fmaf(r0a, wr[0], a);
    a = fmaf(r0b, wr[1], a);
    a = fmaf(r0c, wr[2], a);
    a = fmaf(r1a, wr[3], a);
    a = fmaf(r1b, wr[4], a);
    a = fmaf(r1c, wr[5], a);
    a = fmaf(r2a, wr[6], a);
    a = fmaf(r2b, wr[7], a);
    a = fmaf(r2c, wr[8], a);
    res[r] = a;
    r0a = r1a; r0b = r1b; r0c = r1c;
    r1a = r2a; r1b = r2b; r1c = r2c;
  }
  if (ch < 192) {
    const int qk = ch / 96, c = ch - qk * 96;
    const int bc = b * 96 + c;
    float ss = 0.f;
#pragma unroll
    for (int r = 0; r < 32; ++r) ss = fmaf(res[r], res[r], ss);
    (qk ? nk_p : nq_p)[(size_t)bc * 2048 + hb * 256 + wl] = ss;
    ushort_t* dh = (qk ? kt_hi : qt_hi) + (size_t)bc * NHW + hb * 8192 + wl * 32;
    ushort_t* dl = (qk ? kt_lo : qt_lo) + (size_t)bc * NHW + hb * 8192 + wl * 32;
#pragma unroll
    for (int j4 = 0; j4 < 4; ++j4) {
      uint4 H, L;
      unsigned* ph = (unsigned*)&H;
      unsigned* pl = (unsigned*)&L;
#pragma unroll
      for (int e = 0; e < 4; ++e) {
        const float f0 = res[j4 * 8 + 2 * e], f1 = res[j4 * 8 + 2 * e + 1];
        const ushort_t hh0 = f2bf(f0), hh1 = f2bf(f1);
        ph[e] = (unsigned)hh0 | ((unsigned)hh1 << 16);
        pl[e] = (unsigned)f2bf(f0 - bf2f(hh0)) |
                ((unsigned)f2bf(f1 - bf2f(hh1)) << 16);
      }
      *(uint4*)(dh + j4 * 8) = H;
      *(uint4*)(dl + j4 * 8) = L;
    }
  } else {
    const int bc = b * 96 + (ch - 192);
    const int wb = wl >> 5, wsub = wl & 31;
    ushort_t* dh = v_hi + (size_t)bc * NHW + wb * 8192 + wsub;
    ushort_t* dl = v_lo + (size_t)bc * NHW + wb * 8192 + wsub;
#pragma unroll
    for (int r = 0; r < 32; ++r) {
      const float f = res[r];
      const ushort_t hh = f2bf(f);
      dh[(h0 + r) * 32] = hh;
      dl[(h0 + r) * 32] = f2bf(f - bf2f(hh));
    }
  }
}

// ---------------- attn: S = QT*K (split-bf16 MFMA) * iq*ik*temp,
// col-softmax over w, P -> pt tiled [bc][wb][v][32w] split bf16 ----
__global__ __launch_bounds__(256, 3) void k_attn_mfma(
    const ushort_t* __restrict__ qt_hi, const ushort_t* __restrict__ qt_lo,
    const ushort_t* __restrict__ kt_hi, const ushort_t* __restrict__ kt_lo,
    const float* __restrict__ nq_p, const float* __restrict__ nk_p,
    const float* __restrict__ temp, ushort_t* __restrict__ pt_hi,
    ushort_t* __restrict__ pt_lo) {
  __shared__ __align__(16) char smem[52480];
  ushort_t* qh = (ushort_t*)smem;            // [256][40]
  ushort_t* ql = (ushort_t*)(smem + 20480);  // [256][40]
  ushort_t* kh = (ushort_t*)(smem + 40960);  // [64][40]
  ushort_t* kl = (ushort_t*)(smem + 46080);  // [64][40]
  float* red = (float*)(smem + 51200);       // [256]
  float* iqs = red;                          // alias (time-disjoint)
  float* iks = (float*)(smem + 52224);       // [64]
  ushort_t* pts = (ushort_t*)smem;           // alias: [64][264]

  const int t = threadIdx.x;
  const int lane = t & 63;
  const int wid = t >> 6;
  const int bid = blockIdx.x;
  const int pxb = gridDim.x >> 5;  // bc per XCD
  const int bc = (bid & 7) * pxb + (bid >> 5);
  const int v0 = ((bid >> 3) & 3) * 64;
  const size_t base_q = (size_t)bc * NHW;
  const size_t base_k = (size_t)bc * NHW + (size_t)v0 * 32;

  f32x4 acc[4][4];
#pragma unroll
  for (int mt = 0; mt < 4; ++mt)
#pragma unroll
    for (int nt = 0; nt < 4; ++nt) acc[mt][nt] = (f32x4){0.f, 0.f, 0.f, 0.f};

  for (int hb = 0; hb < 8; ++hb) {
    {
      const ushort_t* gq = qt_hi + base_q + hb * 8192 + t * 32;
      const ushort_t* gl = qt_lo + base_q + hb * 8192 + t * 32;
      uint4* dh = (uint4*)(qh + t * 40);
      uint4* dl = (uint4*)(ql + t * 40);
#pragma unroll
      for (int j = 0; j < 4; ++j) {
        dh[j] = *(const uint4*)(gq + j * 8);
        dl[j] = *(const uint4*)(gl + j * 8);
      }
      if (t < 64) {
        const ushort_t* gk = kt_hi + base_k + hb * 8192 + t * 32;
        uint4* dk = (uint4*)(kh + t * 40);
#pragma unroll
        for (int j = 0; j < 4; ++j) dk[j] = *(const uint4*)(gk + j * 8);
      } else if (t < 128) {
        const int r = t - 64;
        const ushort_t* gk = kt_lo + base_k + hb * 8192 + r * 32;
        uint4* dk = (uint4*)(kl + r * 40);
#pragma unroll
        for (int j = 0; j < 4; ++j) dk[j] = *(const uint4*)(gk + j * 8);
      }
    }
    __syncthreads();
    bf16x8 aH[4], aL[4];
#pragma unroll
    for (int mt = 0; mt < 4; ++mt) {
      const int off = (wid * 64 + mt * 16 + (lane & 15)) * 40 + (lane >> 4) * 8;
      aH[mt] = *(const bf16x8*)(qh + off);
      aL[mt] = *(const bf16x8*)(ql + off);
    }
#pragma unroll
    for (int nt = 0; nt < 4; ++nt) {
      const int off = (nt * 16 + (lane & 15)) * 40 + (lane >> 4) * 8;
      const bf16x8 bH = *(const bf16x8*)(kh + off);
      const bf16x8 bL = *(const bf16x8*)(kl + off);
#pragma unroll
      for (int mt = 0; mt < 4; ++mt) {
        acc[mt][nt] = __builtin_amdgcn_mfma_f32_16x16x32_bf16(aH[mt], bH, acc[mt][nt], 0, 0, 0);
        acc[mt][nt] = __builtin_amdgcn_mfma_f32_16x16x32_bf16(aH[mt], bL, acc[mt][nt], 0, 0, 0);
        acc[mt][nt] = __builtin_amdgcn_mfma_f32_16x16x32_bf16(aL[mt], bH, acc[mt][nt], 0, 0, 0);
      }
    }
    __syncthreads();
  }

  // norms: iq[w] = 1/max(sqrt(sum8),eps); ik[v] = temp/max(sqrt,eps)
  {
    float s8 = 0.f;
    const float* np = nq_p + (size_t)bc * 2048 + t;
#pragma unroll
    for (int hb = 0; hb < 8; ++hb) s8 += np[hb * 256];
    iqs[t] = 1.f / fmaxf(sqrtf(s8), 1e-12f);
    if (t < 64) {
      float sk8 = 0.f;
      const float* nk = nk_p + (size_t)bc * 2048 + v0 + t;
#pragma unroll
      for (int hb = 0; hb < 8; ++hb) sk8 += nk[hb * 256];
      iks[t] = temp[bc % NC] / fmaxf(sqrtf(sk8), 1e-12f);
    }
  }
  __syncthreads();
#pragma unroll
  for (int mt = 0; mt < 4; ++mt) {
    float iq4[4];
#pragma unroll
    for (int r = 0; r < 4; ++r)
      iq4[r] = iqs[wid * 64 + mt * 16 + (lane >> 4) * 4 + r];
#pragma unroll
    for (int nt = 0; nt < 4; ++nt) {
      const float ikv = iks[nt * 16 + (lane & 15)];
#pragma unroll
      for (int r = 0; r < 4; ++r) acc[mt][nt][r] *= iq4[r] * ikv;
    }
  }
  __syncthreads();  // iqs dead; red reused below

  float Mv[4], Sv[4];
#pragma unroll
  for (int nt = 0; nt < 4; ++nt) {
    float m = -3.4e38f;
#pragma unroll
    for (int mt = 0; mt < 4; ++mt)
#pragma unroll
      for (int r = 0; r < 4; ++r) m = fmaxf(m, acc[mt][nt][r]);
    m = fmaxf(m, __shfl_xor(m, 16));
    m = fmaxf(m, __shfl_xor(m, 32));
    if (lane < 16) red[wid * 64 + nt * 16 + lane] = m;
  }
  __syncthreads();
#pragma unroll
  for (int nt = 0; nt < 4; ++nt) {
    const int vl = nt * 16 + (lane & 15);
    Mv[nt] = fmaxf(fmaxf(red[vl], red[64 + vl]),
                   fmaxf(red[128 + vl], red[192 + vl]));
  }
  __syncthreads();
#pragma unroll
  for (int nt = 0; nt < 4; ++nt) {
    float s = 0.f;
#pragma unroll
    for (int mt = 0; mt < 4; ++mt)
#pragma unroll
      for (int r = 0; r < 4; ++r) {
        const float p = __expf(acc[mt][nt][r] - Mv[nt]);
        acc[mt][nt][r] = p;
        s += p;
      }
    s += __shfl_xor(s, 16);
    s += __shfl_xor(s, 32);
    if (lane < 16) red[wid * 64 + nt * 16 + lane] = s;
  }
  __syncthreads();
#pragma unroll
  for (int nt = 0; nt < 4; ++nt) {
    const int vl = nt * 16 + (lane & 15);
    Sv[nt] = 1.f / (red[vl] + red[64 + vl] + red[128 + vl] + red[192 + vl]);
  }
#pragma unroll
  for (int nt = 0; nt < 4; ++nt)
#pragma unroll
    for (int mt = 0; mt < 4; ++mt)
#pragma unroll
      for (int r = 0; r < 4; ++r) acc[mt][nt][r] *= Sv[nt];
  __syncthreads();  // staging fully dead before pts alias write

  for (int pass = 0; pass < 2; ++pass) {
#pragma unroll
    for (int nt = 0; nt < 4; ++nt)
#pragma unroll
      for (int mt = 0; mt < 4; ++mt) {
        ushort_t pk[4];
#pragma unroll
        for (int r = 0; r < 4; ++r) {
          const float p = acc[mt][nt][r];
          const ushort_t hi = f2bf(p);
          pk[r] = pass == 0 ? hi : f2bf(p - bf2f(hi));
        }
        const int v = nt * 16 + (lane & 15);
        const int wb2 = wid * 64 + mt * 16 + ((lane >> 4) << 2);
        *(ushort4*)(pts + v * 264 + wb2) =
            make_ushort4(pk[0], pk[1], pk[2], pk[3]);
      }
    __syncthreads();
    ushort_t* dst = pass == 0 ? pt_hi : pt_lo;
#pragma unroll
    for (int i = 0; i < 2; ++i) {
      const int cid = t + (i << 8);
      const int wb = cid >> 6, v = cid & 63;
      const ushort_t* sp = pts + v * 264 + wb * 32;
      ushort_t* d = dst + (size_t)bc * NHW + (size_t)wb * 8192 +
                    (size_t)(v0 + v) * 32;
#pragma unroll
      for (int j = 0; j < 4; ++j)
        *(uint4*)(d + j * 8) = *(const uint4*)(sp + j * 8);
    }
    __syncthreads();
  }
}

// ---------------- out[h][v] = sum_w V[h][w] * P[w][v], split-bf16 MFMA ----
__global__ __launch_bounds__(256, 3) void k_av_mfma(
    const ushort_t* __restrict__ v_hi, const ushort_t* __restrict__ v_lo,
    const ushort_t* __restrict__ pt_hi, const ushort_t* __restrict__ pt_lo,
    float* __restrict__ aout) {
  __shared__ __align__(16) ushort_t vh[128 * 40];
  __shared__ __align__(16) ushort_t vl[128 * 40];
  __shared__ __align__(16) ushort_t ph[128 * 40];
  __shared__ __align__(16) ushort_t pl[128 * 40];
  const int t = threadIdx.x;
  const int lane = t & 63;
  const int wid = t >> 6;
  const int bid = blockIdx.x;
  const int pxb = gridDim.x >> 5;
  const int bc = (bid & 7) * pxb + (bid >> 5);
  const int tile = (bid >> 3) & 3;
  const int h0 = (tile >> 1) * 128, v0 = (tile & 1) * 128;
  const int wh = wid >> 1, wv = wid & 1;

  f32x4 acc[4][4];
#pragma unroll
  for (int mt = 0; mt < 4; ++mt)
#pragma unroll
    for (int nt = 0; nt < 4; ++nt) acc[mt][nt] = (f32x4){0.f, 0.f, 0.f, 0.f};

  for (int wb = 0; wb < 8; ++wb) {
#pragma unroll
    for (int i = 0; i < 2; ++i) {
      const int id = t + (i << 8);
      const int arr = id >> 7, row = id & 127;
      const ushort_t* g;
      ushort_t* d;
      if (arr == 0) {
        g = v_hi + (size_t)bc * NHW + (size_t)wb * 8192 + (size_t)(h0 + row) * 32;
        d = vh + row * 40;
      } else if (arr == 1) {
        g = v_lo + (size_t)bc * NHW + (size_t)wb * 8192 + (size_t)(h0 + row) * 32;
        d = vl + row * 40;
      } else if (arr == 2) {
        g = pt_hi + (size_t)bc * NHW + (size_t)wb * 8192 + (size_t)(v0 + row) * 32;
        d = ph + row * 40;
      } else {
        g = pt_lo + (size_t)bc * NHW + (size_t)wb * 8192 + (size_t)(v0 + row) * 32;
        d = pl + row * 40;
      }
#pragma unroll
      for (int j = 0; j < 4; ++j)
        *(uint4*)(d + j * 8) = *(const uint4*)(g + j * 8);
    }
    __syncthreads();
    bf16x8 aH[4], aL[4];
#pragma unroll
    for (int mt = 0; mt < 4; ++mt) {
      const int off = (wh * 64 + mt * 16 + (lane & 15)) * 40 + (lane >> 4) * 8;
      aH[mt] = *(const bf16x8*)(vh + off);
      aL[mt] = *(const bf16x8*)(vl + off);
    }
#pragma unroll
    for (int nt = 0; nt < 4; ++nt) {
      const int off = (wv * 64 + nt * 16 + (lane & 15)) * 40 + (lane >> 4) * 8;
      const bf16x8 bH = *(const bf16x8*)(ph + off);
      const bf16x8 bL = *(const bf16x8*)(pl + off);
#pragma unroll
      for (int mt = 0; mt < 4; ++mt) {
        acc[mt][nt] = __builtin_amdgcn_mfma_f32_16x16x32_bf16(aH[mt], bH, acc[mt][nt], 0, 0, 0);
        acc[mt][nt] = __builtin_amdgcn_mfma_f32_16x16x32_bf16(aH[mt], bL, acc[mt][nt], 0, 0, 0);
        acc[mt][nt] = __builtin_amdgcn_mfma_f32_16x16x32_bf16(aL[mt], bH, acc[mt][nt], 0, 0, 0);
      }
    }
    __syncthreads();
  }

#pragma unroll
  for (int mt = 0; mt < 4; ++mt) {
    const int hbase = h0 + wh * 64 + mt * 16 + ((lane >> 4) << 2);
#pragma unroll
    for (int nt = 0; nt < 4; ++nt) {
      const int vv = v0 + wv * 64 + nt * 16 + (lane & 15);
      float* o = aout + (size_t)bc * NHW + (size_t)hbase * NW + vv;
#pragma unroll
      for (int r = 0; r < 4; ++r) o[(size_t)r * NW] = acc[mt][nt][r];
    }
  }
}

extern "C" void kernel_launch(void* const* d_in, const int* in_sizes, int n_in,
                              void* d_out, int out_size, void* d_ws,
                              size_t ws_size, hipStream_t stream) {
  const float* x = (const float*)d_in[0];
  const float* qkv_w = (const float*)d_in[1];
  const float* qkv_b = (const float*)d_in[2];
  const float* dw_w = (const float*)d_in[3];
  const float* dw_b = (const float*)d_in[4];
  const float* temp = (const float*)d_in[5];
  const float* proj_w = (const float*)d_in[6];
  const float* proj_b = (const float*)d_in[7];
  float* out = (float*)d_out;

  // per-batch bytes: qkv_tiled 75,497,472 + 6*HALF(12,582,912) + 2*786,432
  auto need = [](int nb) -> size_t {
    return (size_t)nb * 152567808ull + 147456ull;
  };
  int nb = 1;
  if (need(4) <= ws_size) nb = 4;
  else if (need(2) <= ws_size) nb = 2;

  char* base = (char*)d_ws;
  const size_t QKV_T = (size_t)nb * 75497472ull;
  const size_t HALF = (size_t)nb * 12582912ull;
  const size_t NQB = (size_t)nb * 786432ull;
  float* qkv_tiled = (float*)base;
  // aliases inside qkv_tiled (live only after k_dw3):
  ushort_t* pt_hi = (ushort_t*)base;
  ushort_t* pt_lo = (ushort_t*)(base + HALF);
  float* aout = (float*)(base + 2 * HALF);  // 2*HALF bytes; total 4*HALF <= QKV_T
  char* p = base + QKV_T;
  ushort_t* qt_hi = (ushort_t*)p; p += HALF;
  ushort_t* qt_lo = (ushort_t*)p; p += HALF;
  ushort_t* kt_hi = (ushort_t*)p; p += HALF;
  ushort_t* kt_lo = (ushort_t*)p; p += HALF;
  ushort_t* v_hi = (ushort_t*)p; p += HALF;
  ushort_t* v_lo = (ushort_t*)p; p += HALF;
  float* nq_p = (float*)p; p += NQB;
  float* nk_p = (float*)p; p += NQB;
  ushort_t* wq_hi = (ushort_t*)p; p += 55296;
  ushort_t* wq_lo = (ushort_t*)p; p += 55296;
  ushort_t* wp_hi = (ushort_t*)p; p += 18432;
  ushort_t* wp_lo = (ushort_t*)p;

  k_wprep<<<dim3(144), 256, 0, stream>>>(qkv_w, proj_w, wq_hi, wq_lo, wp_hi, wp_lo);

  const int BC = nb * NC;
  for (int b0 = 0; b0 < 4; b0 += nb) {
    const float* xb = x + (size_t)b0 * NC * NHW;
    float* outb = out + (size_t)b0 * NC * NHW;
    k_conv<NC3, true><<<dim3(1024, nb), 256, 0, stream>>>(
        xb, wq_hi, wq_lo, qkv_b, qkv_tiled);
    k_dw3<<<dim3(8, nb * NC3), 256, 0, stream>>>(
        qkv_tiled, dw_w, dw_b, qt_hi, qt_lo, kt_hi, kt_lo, v_hi, v_lo, nq_p, nk_p);
    k_attn_mfma<<<dim3(BC * 4), 256, 0, stream>>>(
        qt_hi, qt_lo, kt_hi, kt_lo, nq_p, nk_p, temp, pt_hi, pt_lo);
    k_av_mfma<<<dim3(BC * 4), 256, 0, stream>>>(v_hi, v_lo, pt_hi, pt_lo, aout);
    k_conv<NC, false><<<dim3(1024, nb), 256, 0, stream>>>(
        aout, wp_hi, wp_lo, proj_b, outb);
  }
}

// Round 7
// 599.166 us; speedup vs baseline: 1.3763x; 1.1166x over previous
//
#include <hip/hip_runtime.h>

#define NC 96
#define NC3 288
#define NH 256
#define NW 256
#define NHW 65536

typedef unsigned short ushort_t;
typedef __attribute__((ext_vector_type(8))) short bf16x8;
typedef __attribute__((ext_vector_type(4))) float f32x4;

__device__ __forceinline__ ushort_t f2bf(float x) {
  unsigned u = __float_as_uint(x);
  u += 0x7fffu + ((u >> 16) & 1u);
  return (ushort_t)(u >> 16);
}
__device__ __forceinline__ float bf2f(ushort_t h) {
  return __uint_as_float((unsigned)h << 16);
}

// ---------------- weight split-bf16 prep (once per launch) ----------------
__global__ __launch_bounds__(256) void k_wprep(
    const float* __restrict__ qkv_w, const float* __restrict__ proj_w,
    ushort_t* __restrict__ wq_hi, ushort_t* __restrict__ wq_lo,
    ushort_t* __restrict__ wp_hi, ushort_t* __restrict__ wp_lo) {
  const int id = blockIdx.x * 256 + threadIdx.x;
  if (id < NC3 * NC) {
    const float v = qkv_w[id];
    const ushort_t h = f2bf(v);
    wq_hi[id] = h;
    wq_lo[id] = f2bf(v - bf2f(h));
  } else {
    const int j = id - NC3 * NC;  // < NC*NC
    const float v = proj_w[j];
    const ushort_t h = f2bf(v);
    wp_hi[j] = h;
    wp_lo[j] = f2bf(v - bf2f(h));
  }
}

// ---------------- 1x1 conv: fused transpose + split-bf16 MFMA GEMM ----------
template <int OUTC, bool TILED>
__global__ __launch_bounds__(256, 3) void k_conv(
    const float* __restrict__ in, const ushort_t* __restrict__ w_hi,
    const ushort_t* __restrict__ w_lo, const float* __restrict__ bias,
    float* __restrict__ out) {
  __shared__ float xt[96][66];
  __shared__ __align__(16) ushort_t xh[64][104];
  __shared__ __align__(16) ushort_t xl[64][104];
  const int t = threadIdx.x;
  const int bz = blockIdx.y;
  const int sblk = blockIdx.x;
  const int s0 = sblk * 64;
  const float* xb = in + (size_t)bz * NC * NHW + s0;
#pragma unroll
  for (int i = 0; i < 6; ++i) {
    const int idx = t + 256 * i;  // 1536 float4 = 96 rows x 16
    const int row = idx >> 4, c4 = (idx & 15) << 2;
    *(float4*)&xt[row][c4] = *(const float4*)&xb[(size_t)row * NHW + c4];
  }
  __syncthreads();
  {
    const int s = t & 63, cg = t >> 6;
#pragma unroll
    for (int i = 0; i < 12; ++i) {
      const int c = cg * 24 + i * 2;
      const float f0 = xt[c][s], f1 = xt[c + 1][s];
      const ushort_t h0 = f2bf(f0), h1 = f2bf(f1);
      const ushort_t l0 = f2bf(f0 - bf2f(h0)), l1 = f2bf(f1 - bf2f(h1));
      *(unsigned*)&xh[s][c] = (unsigned)h0 | ((unsigned)h1 << 16);
      *(unsigned*)&xl[s][c] = (unsigned)l0 | ((unsigned)l1 << 16);
    }
  }
  __syncthreads();
  const int lane = t & 63, wave = t >> 6;
  bf16x8 bH[3], bL[3];
  {
    const int srow = wave * 16 + (lane & 15);
    const int kof = (lane >> 4) * 8;
#pragma unroll
    for (int kk = 0; kk < 3; ++kk) {
      bH[kk] = *(const bf16x8*)&xh[srow][kk * 32 + kof];
      bL[kk] = *(const bf16x8*)&xl[srow][kk * 32 + kof];
    }
  }
  constexpr int M = OUTC / 16;
  f32x4 acc[M];
#pragma unroll
  for (int m = 0; m < M; ++m) acc[m] = (f32x4){0.f, 0.f, 0.f, 0.f};
  const int akof = (lane >> 4) * 8;
#pragma unroll
  for (int kk = 0; kk < 3; ++kk) {
#pragma unroll
    for (int m = 0; m < M; ++m) {
      const int wi = (m * 16 + (lane & 15)) * NC + kk * 32 + akof;
      const bf16x8 aH = *(const bf16x8*)(w_hi + wi);
      const bf16x8 aL = *(const bf16x8*)(w_lo + wi);
      acc[m] = __builtin_amdgcn_mfma_f32_16x16x32_bf16(aH, bH[kk], acc[m], 0, 0, 0);
      acc[m] = __builtin_amdgcn_mfma_f32_16x16x32_bf16(aH, bL[kk], acc[m], 0, 0, 0);
      acc[m] = __builtin_amdgcn_mfma_f32_16x16x32_bf16(aL, bH[kk], acc[m], 0, 0, 0);
    }
  }
  const int sl = wave * 16 + (lane & 15);
  if (TILED) {
    float* ob = out + ((size_t)(bz * 1024 + sblk)) * OUTC * 64 + sl;
#pragma unroll
    for (int m = 0; m < M; ++m) {
      const int o2 = m * 16 + (lane >> 4) * 4;
#pragma unroll
      for (int r = 0; r < 4; ++r)
        ob[(size_t)(o2 + r) * 64] = acc[m][r] + bias[o2 + r];
    }
  } else {
    float* ob = out + (size_t)bz * OUTC * NHW + s0 + sl;
#pragma unroll
    for (int m = 0; m < M; ++m) {
      const int o2 = m * 16 + (lane >> 4) * 4;
#pragma unroll
      for (int r = 0; r < 4; ++r)
        ob[(size_t)(o2 + r) * NHW] = acc[m][r] + bias[o2 + r];
    }
  }
}

// ---------------- depthwise 3x3 + layout emit + norm partials ----------------
// Block: one ch, 16 h x 256 w band. Reads tiled qkv [b*1024+chunk][288][64].
// q/k -> qt/kt [bc][hb32][w][32h] split bf16 + nq/nk partials [bc][16][256]
// v   -> v_pk  [bc][wb][h][32w] u32 (hi|lo<<16)
__global__ __launch_bounds__(256, 8) void k_dw3(
    const float* __restrict__ qkvt, const float* __restrict__ w,
    const float* __restrict__ bias, ushort_t* __restrict__ qt_hi,
    ushort_t* __restrict__ qt_lo, ushort_t* __restrict__ kt_hi,
    ushort_t* __restrict__ kt_lo, unsigned* __restrict__ v_pk,
    float* __restrict__ nq_p, float* __restrict__ nk_p) {
  __shared__ float sd[18][264];  // cols: 3 = gw-1 halo(=0), 4..259 = gw 0..255, 260 = halo(=0)
  const int t = threadIdx.x;
  const int hb = blockIdx.x;   // 16 bands of 16 h
  const int bcc = blockIdx.y;
  const int b = bcc / NC3, ch = bcc % NC3;
  const int h0 = hb * 16;
  const float* src = qkvt + (size_t)b * 1024 * NC3 * 64 + (size_t)ch * 64;
  // interior fill: 18 rows x 64 float4 (aligned), no division
#pragma unroll
  for (int i = 0; i < 5; ++i) {
    const int idx = t + 256 * i;  // < 1152 = 18*64
    if (idx < 18 * 64) {
      const int r = idx >> 6, j = idx & 63;
      const int gh = h0 + r - 1;
      float4 v = make_float4(0.f, 0.f, 0.f, 0.f);
      if (gh >= 0 && gh < 256) {
        const int gw = 4 * j;
        v = *(const float4*)&src[(size_t)(gh * 4 + (gw >> 6)) * (NC3 * 64) +
                                 (gw & 63)];
      }
      *(float4*)&sd[r][4 + 4 * j] = v;
    }
  }
  // w-halo columns are always outside the image -> zero
  if (t < 36) {
    const int r = t >> 1;
    sd[r][(t & 1) ? 260 : 3] = 0.f;
  }
  __syncthreads();
  float wr[9];
#pragma unroll
  for (int k = 0; k < 9; ++k) wr[k] = w[ch * 9 + k];
  const float bs = bias[ch];
  const int wl = t;
  float res[16];
  float r0a = sd[0][wl + 3], r0b = sd[0][wl + 4], r0c = sd[0][wl + 5];
  float r1a = sd[1][wl + 3], r1b = sd[1][wl + 4], r1c = sd[1][wl + 5];
#pragma unroll
  for (int r = 0; r < 16; ++r) {
    const float r2a = sd[r + 2][wl + 3], r2b = sd[r + 2][wl + 4],
                r2c = sd[r + 2][wl + 5];
    float a = bs;
    a = fmaf(r0a, wr[0], a);
    a = fmaf(r0b, wr[1], a);
    a = fmaf(r0c, wr[2], a);
    a = fmaf(r1a, wr[3], a);
    a = fmaf(r1b, wr[4], a);
    a = fmaf(r1c, wr[5], a);
    a = fmaf(r2a, wr[6], a);
    a = fmaf(r2b, wr[7], a);
    a = fmaf(r2c, wr[8], a);
    res[r] = a;
    r0a = r1a; r0b = r1b; r0c = r1c;
    r1a = r2a; r1b = r2b; r1c = r2c;
  }
  if (ch < 192) {
    const int qk = ch / 96, c = ch - qk * 96;
    const int bc = b * 96 + c;
    float ss = 0.f;
#pragma unroll
    for (int r = 0; r < 16; ++r) ss = fmaf(res[r], res[r], ss);
    (qk ? nk_p : nq_p)[(size_t)bc * 4096 + hb * 256 + wl] = ss;
    const size_t tb = (size_t)bc * NHW + (hb >> 1) * 8192 + (size_t)wl * 32 +
                      (hb & 1) * 16;
    ushort_t* dh = (qk ? kt_hi : qt_hi) + tb;
    ushort_t* dl = (qk ? kt_lo : qt_lo) + tb;
#pragma unroll
    for (int j4 = 0; j4 < 2; ++j4) {
      uint4 H, L;
      unsigned* ph = (unsigned*)&H;
      unsigned* pl = (unsigned*)&L;
#pragma unroll
      for (int e = 0; e < 4; ++e) {
        const float f0 = res[j4 * 8 + 2 * e], f1 = res[j4 * 8 + 2 * e + 1];
        const ushort_t hh0 = f2bf(f0), hh1 = f2bf(f1);
        ph[e] = (unsigned)hh0 | ((unsigned)hh1 << 16);
        pl[e] = (unsigned)f2bf(f0 - bf2f(hh0)) |
                ((unsigned)f2bf(f1 - bf2f(hh1)) << 16);
      }
      *(uint4*)(dh + j4 * 8) = H;
      *(uint4*)(dl + j4 * 8) = L;
    }
  } else {
    const int bc = b * 96 + (ch - 192);
    const int wb = wl >> 5, wsub = wl & 31;
    unsigned* dp = v_pk + (size_t)bc * NHW + wb * 8192 + wsub;
#pragma unroll
    for (int r = 0; r < 16; ++r) {
      const float f = res[r];
      const ushort_t hh = f2bf(f);
      dp[(h0 + r) * 32] = (unsigned)hh | ((unsigned)f2bf(f - bf2f(hh)) << 16);
    }
  }
}

// ---------------- attn: S = QT*K (split-bf16 MFMA) * iq*ik*temp,
// col-softmax over w, P -> pt tiled [bc][wb][v][32w] split bf16 ----
__global__ __launch_bounds__(256, 3) void k_attn_mfma(
    const ushort_t* __restrict__ qt_hi, const ushort_t* __restrict__ qt_lo,
    const ushort_t* __restrict__ kt_hi, const ushort_t* __restrict__ kt_lo,
    const float* __restrict__ nq_p, const float* __restrict__ nk_p,
    const float* __restrict__ temp, ushort_t* __restrict__ pt_hi,
    ushort_t* __restrict__ pt_lo) {
  __shared__ __align__(16) char smem[52480];
  ushort_t* qh = (ushort_t*)smem;            // [256][40]
  ushort_t* ql = (ushort_t*)(smem + 20480);  // [256][40]
  ushort_t* kh = (ushort_t*)(smem + 40960);  // [64][40]
  ushort_t* kl = (ushort_t*)(smem + 46080);  // [64][40]
  float* red = (float*)(smem + 51200);       // [256]
  float* iqs = red;                          // alias (time-disjoint)
  float* iks = (float*)(smem + 52224);       // [64]
  ushort_t* pts = (ushort_t*)smem;           // alias: [64][264]

  const int t = threadIdx.x;
  const int lane = t & 63;
  const int wid = t >> 6;
  const int bid = blockIdx.x;
  const int pxb = gridDim.x >> 5;  // bc per XCD
  const int bc = (bid & 7) * pxb + (bid >> 5);
  const int v0 = ((bid >> 3) & 3) * 64;
  const size_t base_q = (size_t)bc * NHW;
  const size_t base_k = (size_t)bc * NHW + (size_t)v0 * 32;

  f32x4 acc[4][4];
#pragma unroll
  for (int mt = 0; mt < 4; ++mt)
#pragma unroll
    for (int nt = 0; nt < 4; ++nt) acc[mt][nt] = (f32x4){0.f, 0.f, 0.f, 0.f};

  for (int hb = 0; hb < 8; ++hb) {
    {
      const ushort_t* gq = qt_hi + base_q + hb * 8192 + t * 32;
      const ushort_t* gl = qt_lo + base_q + hb * 8192 + t * 32;
      uint4* dh = (uint4*)(qh + t * 40);
      uint4* dl = (uint4*)(ql + t * 40);
#pragma unroll
      for (int j = 0; j < 4; ++j) {
        dh[j] = *(const uint4*)(gq + j * 8);
        dl[j] = *(const uint4*)(gl + j * 8);
      }
      if (t < 64) {
        const ushort_t* gk = kt_hi + base_k + hb * 8192 + t * 32;
        uint4* dk = (uint4*)(kh + t * 40);
#pragma unroll
        for (int j = 0; j < 4; ++j) dk[j] = *(const uint4*)(gk + j * 8);
      } else if (t < 128) {
        const int r = t - 64;
        const ushort_t* gk = kt_lo + base_k + hb * 8192 + r * 32;
        uint4* dk = (uint4*)(kl + r * 40);
#pragma unroll
        for (int j = 0; j < 4; ++j) dk[j] = *(const uint4*)(gk + j * 8);
      }
    }
    __syncthreads();
    bf16x8 aH[4], aL[4];
#pragma unroll
    for (int mt = 0; mt < 4; ++mt) {
      const int off = (wid * 64 + mt * 16 + (lane & 15)) * 40 + (lane >> 4) * 8;
      aH[mt] = *(const bf16x8*)(qh + off);
      aL[mt] = *(const bf16x8*)(ql + off);
    }
#pragma unroll
    for (int nt = 0; nt < 4; ++nt) {
      const int off = (nt * 16 + (lane & 15)) * 40 + (lane >> 4) * 8;
      const bf16x8 bH = *(const bf16x8*)(kh + off);
      const bf16x8 bL = *(const bf16x8*)(kl + off);
#pragma unroll
      for (int mt = 0; mt < 4; ++mt) {
        acc[mt][nt] = __builtin_amdgcn_mfma_f32_16x16x32_bf16(aH[mt], bH, acc[mt][nt], 0, 0, 0);
        acc[mt][nt] = __builtin_amdgcn_mfma_f32_16x16x32_bf16(aH[mt], bL, acc[mt][nt], 0, 0, 0);
        acc[mt][nt] = __builtin_amdgcn_mfma_f32_16x16x32_bf16(aL[mt], bH, acc[mt][nt], 0, 0, 0);
      }
    }
    __syncthreads();
  }

  // norms: iq[w] = 1/max(sqrt(sum16),eps); ik[v] = temp/max(sqrt,eps)
  {
    float s8 = 0.f;
    const float* np = nq_p + (size_t)bc * 4096 + t;
#pragma unroll
    for (int hb = 0; hb < 16; ++hb) s8 += np[hb * 256];
    iqs[t] = 1.f / fmaxf(sqrtf(s8), 1e-12f);
    if (t < 64) {
      float sk8 = 0.f;
      const float* nk = nk_p + (size_t)bc * 4096 + v0 + t;
#pragma unroll
      for (int hb = 0; hb < 16; ++hb) sk8 += nk[hb * 256];
      iks[t] = temp[bc % NC] / fmaxf(sqrtf(sk8), 1e-12f);
    }
  }
  __syncthreads();
#pragma unroll
  for (int mt = 0; mt < 4; ++mt) {
    float iq4[4];
#pragma unroll
    for (int r = 0; r < 4; ++r)
      iq4[r] = iqs[wid * 64 + mt * 16 + (lane >> 4) * 4 + r];
#pragma unroll
    for (int nt = 0; nt < 4; ++nt) {
      const float ikv = iks[nt * 16 + (lane & 15)];
#pragma unroll
      for (int r = 0; r < 4; ++r) acc[mt][nt][r] *= iq4[r] * ikv;
    }
  }
  __syncthreads();  // iqs dead; red reused below

  float Mv[4], Sv[4];
#pragma unroll
  for (int nt = 0; nt < 4; ++nt) {
    float m = -3.4e38f;
#pragma unroll
    for (int mt = 0; mt < 4; ++mt)
#pragma unroll
      for (int r = 0; r < 4; ++r) m = fmaxf(m, acc[mt][nt][r]);
    m = fmaxf(m, __shfl_xor(m, 16));
    m = fmaxf(m, __shfl_xor(m, 32));
    if (lane < 16) red[wid * 64 + nt * 16 + lane] = m;
  }
  __syncthreads();
#pragma unroll
  for (int nt = 0; nt < 4; ++nt) {
    const int vl = nt * 16 + (lane & 15);
    Mv[nt] = fmaxf(fmaxf(red[vl], red[64 + vl]),
                   fmaxf(red[128 + vl], red[192 + vl]));
  }
  __syncthreads();
#pragma unroll
  for (int nt = 0; nt < 4; ++nt) {
    float s = 0.f;
#pragma unroll
    for (int mt = 0; mt < 4; ++mt)
#pragma unroll
      for (int r = 0; r < 4; ++r) {
        const float p = __expf(acc[mt][nt][r] - Mv[nt]);
        acc[mt][nt][r] = p;
        s += p;
      }
    s += __shfl_xor(s, 16);
    s += __shfl_xor(s, 32);
    if (lane < 16) red[wid * 64 + nt * 16 + lane] = s;
  }
  __syncthreads();
#pragma unroll
  for (int nt = 0; nt < 4; ++nt) {
    const int vl = nt * 16 + (lane & 15);
    Sv[nt] = 1.f / (red[vl] + red[64 + vl] + red[128 + vl] + red[192 + vl]);
  }
#pragma unroll
  for (int nt = 0; nt < 4; ++nt)
#pragma unroll
    for (int mt = 0; mt < 4; ++mt)
#pragma unroll
      for (int r = 0; r < 4; ++r) acc[mt][nt][r] *= Sv[nt];
  __syncthreads();  // staging fully dead before pts alias write

  for (int pass = 0; pass < 2; ++pass) {
#pragma unroll
    for (int nt = 0; nt < 4; ++nt)
#pragma unroll
      for (int mt = 0; mt < 4; ++mt) {
        ushort_t pk[4];
#pragma unroll
        for (int r = 0; r < 4; ++r) {
          const float p = acc[mt][nt][r];
          const ushort_t hi = f2bf(p);
          pk[r] = pass == 0 ? hi : f2bf(p - bf2f(hi));
        }
        const int v = nt * 16 + (lane & 15);
        const int wb2 = wid * 64 + mt * 16 + ((lane >> 4) << 2);
        *(ushort4*)(pts + v * 264 + wb2) =
            make_ushort4(pk[0], pk[1], pk[2], pk[3]);
      }
    __syncthreads();
    ushort_t* dst = pass == 0 ? pt_hi : pt_lo;
#pragma unroll
    for (int i = 0; i < 2; ++i) {
      const int cid = t + (i << 8);
      const int wb = cid >> 6, v = cid & 63;
      const ushort_t* sp = pts + v * 264 + wb * 32;
      ushort_t* d = dst + (size_t)bc * NHW + (size_t)wb * 8192 +
                    (size_t)(v0 + v) * 32;
#pragma unroll
      for (int j = 0; j < 4; ++j)
        *(uint4*)(d + j * 8) = *(const uint4*)(sp + j * 8);
    }
    __syncthreads();
  }
}

// ---------------- out[h][v] = sum_w V[h][w] * P[w][v], split-bf16 MFMA ----
__global__ __launch_bounds__(256, 3) void k_av_mfma(
    const unsigned* __restrict__ v_pk, const ushort_t* __restrict__ pt_hi,
    const ushort_t* __restrict__ pt_lo, float* __restrict__ aout) {
  __shared__ __align__(16) ushort_t vh[128 * 40];
  __shared__ __align__(16) ushort_t vl[128 * 40];
  __shared__ __align__(16) ushort_t ph[128 * 40];
  __shared__ __align__(16) ushort_t pl[128 * 40];
  const int t = threadIdx.x;
  const int lane = t & 63;
  const int wid = t >> 6;
  const int bid = blockIdx.x;
  const int pxb = gridDim.x >> 5;
  const int bc = (bid & 7) * pxb + (bid >> 5);
  const int tile = (bid >> 3) & 3;
  const int h0 = (tile >> 1) * 128, v0 = (tile & 1) * 128;
  const int wh = wid >> 1, wv = wid & 1;

  f32x4 acc[4][4];
#pragma unroll
  for (int mt = 0; mt < 4; ++mt)
#pragma unroll
    for (int nt = 0; nt < 4; ++nt) acc[mt][nt] = (f32x4){0.f, 0.f, 0.f, 0.f};

  for (int wb = 0; wb < 8; ++wb) {
    // V: 1024 uint4 of packed u32, unpack to vh/vl
#pragma unroll
    for (int i = 0; i < 4; ++i) {
      const int id = t + (i << 8);
      const int row = id >> 3, q = id & 7;
      const uint4 pk = *(const uint4*)(v_pk + (size_t)bc * NHW + wb * 8192 +
                                       (size_t)(h0 + row) * 32 + q * 4);
      const ushort4 hi4 =
          make_ushort4((ushort_t)(pk.x & 0xffff), (ushort_t)(pk.y & 0xffff),
                       (ushort_t)(pk.z & 0xffff), (ushort_t)(pk.w & 0xffff));
      const ushort4 lo4 =
          make_ushort4((ushort_t)(pk.x >> 16), (ushort_t)(pk.y >> 16),
                       (ushort_t)(pk.z >> 16), (ushort_t)(pk.w >> 16));
      *(ushort4*)(vh + row * 40 + q * 4) = hi4;
      *(ushort4*)(vl + row * 40 + q * 4) = lo4;
    }
    // P: 1024 uint4 copies
#pragma unroll
    for (int i = 0; i < 4; ++i) {
      const int id = t + (i << 8);
      const int arr = id >> 9, rem = id & 511;
      const int row = rem >> 2, q = rem & 3;
      const ushort_t* g = (arr ? pt_lo : pt_hi) + (size_t)bc * NHW +
                          wb * 8192 + (size_t)(v0 + row) * 32 + q * 8;
      ushort_t* d = (arr ? pl : ph) + row * 40 + q * 8;
      *(uint4*)d = *(const uint4*)g;
    }
    __syncthreads();
    bf16x8 aH[4], aL[4];
#pragma unroll
    for (int mt = 0; mt < 4; ++mt) {
      const int off = (wh * 64 + mt * 16 + (lane & 15)) * 40 + (lane >> 4) * 8;
      aH[mt] = *(const bf16x8*)(vh + off);
      aL[mt] = *(const bf16x8*)(vl + off);
    }
#pragma unroll
    for (int nt = 0; nt < 4; ++nt) {
      const int off = (wv * 64 + nt * 16 + (lane & 15)) * 40 + (lane >> 4) * 8;
      const bf16x8 bH = *(const bf16x8*)(ph + off);
      const bf16x8 bL = *(const bf16x8*)(pl + off);
#pragma unroll
      for (int mt = 0; mt < 4; ++mt) {
        acc[mt][nt] = __builtin_amdgcn_mfma_f32_16x16x32_bf16(aH[mt], bH, acc[mt][nt], 0, 0, 0);
        acc[mt][nt] = __builtin_amdgcn_mfma_f32_16x16x32_bf16(aH[mt], bL, acc[mt][nt], 0, 0, 0);
        acc[mt][nt] = __builtin_amdgcn_mfma_f32_16x16x32_bf16(aL[mt], bH, acc[mt][nt], 0, 0, 0);
      }
    }
    __syncthreads();
  }

#pragma unroll
  for (int mt = 0; mt < 4; ++mt) {
    const int hbase = h0 + wh * 64 + mt * 16 + ((lane >> 4) << 2);
#pragma unroll
    for (int nt = 0; nt < 4; ++nt) {
      const int vv = v0 + wv * 64 + nt * 16 + (lane & 15);
      float* o = aout + (size_t)bc * NHW + (size_t)hbase * NW + vv;
#pragma unroll
      for (int r = 0; r < 4; ++r) o[(size_t)r * NW] = acc[mt][nt][r];
    }
  }
}

extern "C" void kernel_launch(void* const* d_in, const int* in_sizes, int n_in,
                              void* d_out, int out_size, void* d_ws,
                              size_t ws_size, hipStream_t stream) {
  const float* x = (const float*)d_in[0];
  const float* qkv_w = (const float*)d_in[1];
  const float* qkv_b = (const float*)d_in[2];
  const float* dw_w = (const float*)d_in[3];
  const float* dw_b = (const float*)d_in[4];
  const float* temp = (const float*)d_in[5];
  const float* proj_w = (const float*)d_in[6];
  const float* proj_b = (const float*)d_in[7];
  float* out = (float*)d_out;

  // per-batch bytes: qkv_tiled 75,497,472 + 6*HALF(12,582,912) + 2*NQB(1,572,864)
  auto need = [](int nb) -> size_t {
    return (size_t)nb * 154140672ull + 147456ull;
  };
  int nb = 1;
  if (need(4) <= ws_size) nb = 4;
  else if (need(2) <= ws_size) nb = 2;

  char* base = (char*)d_ws;
  const size_t QKV_T = (size_t)nb * 75497472ull;
  const size_t HALF = (size_t)nb * 12582912ull;
  const size_t NQB = (size_t)nb * 1572864ull;
  float* qkv_tiled = (float*)base;
  // aliases inside qkv_tiled (live only after k_dw3):
  ushort_t* pt_hi = (ushort_t*)base;
  ushort_t* pt_lo = (ushort_t*)(base + HALF);
  float* aout = (float*)(base + 2 * HALF);  // 2*HALF bytes; 4*HALF <= QKV_T
  char* p = base + QKV_T;
  ushort_t* qt_hi = (ushort_t*)p; p += HALF;
  ushort_t* qt_lo = (ushort_t*)p; p += HALF;
  ushort_t* kt_hi = (ushort_t*)p; p += HALF;
  ushort_t* kt_lo = (ushort_t*)p; p += HALF;
  unsigned* v_pk = (unsigned*)p; p += 2 * HALF;
  float* nq_p = (float*)p; p += NQB;
  float* nk_p = (float*)p; p += NQB;
  ushort_t* wq_hi = (ushort_t*)p; p += 55296;
  ushort_t* wq_lo = (ushort_t*)p; p += 55296;
  ushort_t* wp_hi = (ushort_t*)p; p += 18432;
  ushort_t* wp_lo = (ushort_t*)p;

  k_wprep<<<dim3(144), 256, 0, stream>>>(qkv_w, proj_w, wq_hi, wq_lo, wp_hi, wp_lo);

  const int BC = nb * NC;
  for (int b0 = 0; b0 < 4; b0 += nb) {
    const float* xb = x + (size_t)b0 * NC * NHW;
    float* outb = out + (size_t)b0 * NC * NHW;
    k_conv<NC3, true><<<dim3(1024, nb), 256, 0, stream>>>(
        xb, wq_hi, wq_lo, qkv_b, qkv_tiled);
    k_dw3<<<dim3(16, nb * NC3), 256, 0, stream>>>(
        qkv_tiled, dw_w, dw_b, qt_hi, qt_lo, kt_hi, kt_lo, v_pk, nq_p, nk_p);
    k_attn_mfma<<<dim3(BC * 4), 256, 0, stream>>>(
        qt_hi, qt_lo, kt_hi, kt_lo, nq_p, nk_p, temp, pt_hi, pt_lo);
    k_av_mfma<<<dim3(BC * 4), 256, 0, stream>>>(v_pk, pt_hi, pt_lo, aout);
    k_conv<NC, false><<<dim3(1024, nb), 256, 0, stream>>>(
        aout, wp_hi, wp_lo, proj_b, outb);
  }
}